// Round 17
// baseline (426.907 us; speedup 1.0000x reference)
//
#include <hip/hip_runtime.h>
#include <hip/hip_bf16.h>

typedef __attribute__((ext_vector_type(4))) float f32x4;
typedef __attribute__((ext_vector_type(8))) short bf16x8;
typedef __attribute__((ext_vector_type(4))) short s16x4;

#define BA 48
#define BB 48
#define SS 96
#define DIN 768
#define HH 256

static __device__ __forceinline__ short f2bf(float f) {
    __hip_bfloat16 h = __float2bfloat16(f);
    return *reinterpret_cast<short*>(&h);
}

static __device__ __forceinline__ unsigned pk2bf(float lo, float hi) {
    return ((unsigned)(unsigned short)f2bf(hi) << 16) | (unsigned)(unsigned short)f2bf(lo);
}
static __device__ __forceinline__ float ubflo(unsigned p) { return __uint_as_float(p << 16); }
static __device__ __forceinline__ float ubfhi(unsigned p) { return __uint_as_float(p & 0xffff0000u); }

static __device__ __forceinline__ f32x4 mfma16(bf16x8 a, bf16x8 b, f32x4 c) {
    return __builtin_amdgcn_mfma_f32_16x16x32_bf16(a, b, c, 0, 0, 0);
}

// ---------------------------------------------------------------------------
// Kernel 0: prep — fused {xbf: X f32->bf16, blocks 0..3455} and
// {wt: W transpose+convert, blocks 3456..3599}. (R14-proven-safe component.)
// ---------------------------------------------------------------------------
__global__ __launch_bounds__(256) void prep_kernel(
    const float* __restrict__ Xa, const float* __restrict__ Xb,
    const float* __restrict__ Wq, const float* __restrict__ Wk,
    const float* __restrict__ Wv,
    short* __restrict__ xa, short* __restrict__ xb, short* __restrict__ wt) {
    __shared__ float tile[64][65];
    int bx = blockIdx.x;
    if (bx < 3456) {
        size_t i = (size_t)bx * 256 + threadIdx.x;
        const float* src;
        short* dst;
        size_t off;
        if (i < 442368) { src = Xa; dst = xa; off = i * 8; }
        else            { src = Xb; dst = xb; off = (i - 442368) * 8; }
        f32x4 a = *reinterpret_cast<const f32x4*>(src + off);
        f32x4 b = *reinterpret_cast<const f32x4*>(src + off + 4);
        bf16x8 o;
        o[0] = f2bf(a[0]); o[1] = f2bf(a[1]); o[2] = f2bf(a[2]); o[3] = f2bf(a[3]);
        o[4] = f2bf(b[0]); o[5] = f2bf(b[1]); o[6] = f2bf(b[2]); o[7] = f2bf(b[3]);
        *reinterpret_cast<bf16x8*>(dst + off) = o;
    } else {
        int tt = bx - 3456;                 // 0..143
        int k0 = (tt % 12) * 64;
        int n0 = ((tt / 12) % 4) * 64;
        int mat = tt / 48;
        const float* W = (mat == 0) ? Wq : (mat == 1) ? Wk : Wv;
        int t = threadIdx.x;
#pragma unroll
        for (int j = 0; j < 16; ++j) {
            int kk = j * 4 + (t >> 6);
            int nn = t & 63;
            tile[kk][nn] = W[(size_t)(k0 + kk) * HH + n0 + nn];
        }
        __syncthreads();
#pragma unroll
        for (int j = 0; j < 4; ++j) {
            int nn = j * 16 + (t >> 4);
            int kk = (t & 15) * 4;
            s16x4 pk;
#pragma unroll
            for (int i = 0; i < 4; ++i) pk[i] = f2bf(tile[kk + i][nn]);
            *reinterpret_cast<s16x4*>(&wt[(size_t)(mat * HH + n0 + nn) * DIN + k0 + kk]) = pk;
        }
    }
}

// ---------------------------------------------------------------------------
// Kernel 1: QKV projection from bf16 X. grid (48, 3, 8): 32-col tiles.
// ---------------------------------------------------------------------------
__global__ __launch_bounds__(384) void qkv_kernel(
    const short* __restrict__ xa, const short* __restrict__ xb,
    const float* __restrict__ bq, const float* __restrict__ bk, const float* __restrict__ bv,
    const short* __restrict__ wt,
    float* __restrict__ q_ws, float* __restrict__ k_ws, short* __restrict__ vt_ws) {
    __shared__ short vtile[32][104];

    int bb = blockIdx.x;
    int mat = blockIdx.y;
    int c0 = blockIdx.z * 32;
    int tid = threadIdx.x;
    int wave = tid >> 6, lane = tid & 63;
    int c = lane & 15, g = lane >> 4;

    const short* X = ((mat == 0) ? xa : xb) + (size_t)bb * SS * DIN;
    const short* Wt = wt + (size_t)mat * HH * DIN;
    const float* bias = (mat == 0) ? bq : (mat == 1) ? bk : bv;

    const f32x4 z4 = {0.f, 0.f, 0.f, 0.f};
    f32x4 acc[2];
    acc[0] = z4; acc[1] = z4;

    const short* ap = X + (16 * wave + c) * DIN + g * 8;
    const short* bp = Wt + (c0 + c) * DIN + g * 8;
    for (int kk = 0; kk < DIN; kk += 32) {
        bf16x8 af = *reinterpret_cast<const bf16x8*>(ap + kk);
#pragma unroll
        for (int n = 0; n < 2; ++n) {
            bf16x8 bf = *reinterpret_cast<const bf16x8*>(bp + n * 16 * DIN + kk);
            acc[n] = mfma16(af, bf, acc[n]);
        }
    }
#pragma unroll
    for (int n = 0; n < 2; ++n) {
        float bv_ = bias[c0 + n * 16 + c];
#pragma unroll
        for (int r = 0; r < 4; ++r) acc[n][r] += bv_;
    }

    if (mat < 2) {
        float* dst = (mat == 0) ? q_ws : k_ws;
#pragma unroll
        for (int n = 0; n < 2; ++n)
#pragma unroll
            for (int r = 0; r < 4; ++r)
                dst[(bb * SS + 16 * wave + 4 * g + r) * HH + c0 + n * 16 + c] = acc[n][r];
    } else {
#pragma unroll
        for (int n = 0; n < 2; ++n)
#pragma unroll
            for (int r = 0; r < 4; ++r)
                vtile[n * 16 + c][16 * wave + 4 * g + r] = f2bf(acc[n][r]);
        __syncthreads();
        {
            int t = tid;                 // 384 = 32 d x 12 ch exactly
            int d = t / 12, ch = t % 12;
            bf16x8 pk = *reinterpret_cast<const bf16x8*>(&vtile[d][ch * 8]);
            *reinterpret_cast<bf16x8*>(vt_ws + ((size_t)(bb * HH) + c0 + d) * SS + ch * 8) = pk;
        }
    }
}

// ---------------------------------------------------------------------------
// Kernel 2: row L2 norms for q,k -> qn,kn bf16. One wave per row.
// ---------------------------------------------------------------------------
__global__ __launch_bounds__(256) void norm_kernel(
    const float* __restrict__ q_ws, const float* __restrict__ k_ws,
    short* __restrict__ qn_ws, short* __restrict__ kn_ws) {
    int row = blockIdx.x * 4 + (threadIdx.x >> 6);
    int lane = threadIdx.x & 63;
    int isq = (row < 4608);
    const float* src = isq ? q_ws : k_ws;
    short* dst = isq ? qn_ws : kn_ws;
    int r = isq ? row : row - 4608;

    f32x4 v = *reinterpret_cast<const f32x4*>(src + (size_t)r * HH + lane * 4);
    float s = v[0] * v[0] + v[1] * v[1] + v[2] * v[2] + v[3] * v[3];
#pragma unroll
    for (int m = 1; m < 64; m <<= 1) s += __shfl_xor(s, m);
    float inv = 1.0f / fmaxf(sqrtf(s), 1e-8f);
    s16x4 o;
#pragma unroll
    for (int j = 0; j < 4; ++j) o[j] = f2bf(v[j] * inv);
    *reinterpret_cast<s16x4*>(dst + (size_t)r * HH + lane * 4) = o;
}

// ---------------------------------------------------------------------------
// Kernel 3a: sink2_kernel — TWO PAIRS PER WAVE via bf16-packed K0 (R12 math,
// validated absmax; spill there was the forced (64,4) cap, NOT the packing).
// Wave handles (a=al, b) and (a=al+24, b): shared kn_b (kf L1 hits), two
// independent Sinkhorn chains interleaved for ILP. Kp[2][6][6][2]=144 VGPR +
// v[2][6] (48) + u (12) ~ 225 live < (256,2) cap — NO forced occupancy cap.
// 1152 waves = 0.56 residency rounds (vs 1.125 before -> the 2x chain).
// Zero barriers, zero LDS. SPILL DETECTOR: WRITE_SIZE must stay 41472 KB.
// ---------------------------------------------------------------------------
__global__ __launch_bounds__(256, 2) void sink2_kernel(
    const short* __restrict__ qn_ws, const short* __restrict__ kn_ws,
    short* __restrict__ t_ws) {
    int wave = threadIdx.x >> 6, lane = threadIdx.x & 63;
    int c = lane & 15, g = lane >> 4;
    int b = blockIdx.x * 4 + wave;   // 0..47
    int al = blockIdx.y;             // 0..23; pairs a = al, al+24

    const short* kbase = kn_ws + (size_t)(b * SS) * HH + c * HH + g * 8;
    const f32x4 z4 = {0.f, 0.f, 0.f, 0.f};
    const float L2E10 = 14.4269504088896341f;

    unsigned Kp[2][6][6][2];

    // ---- QK^T per pair, ti-chunked (acc[6]=24 f32 live), exp2, pack bf16 ----
#pragma unroll
    for (int p = 0; p < 2; ++p) {
        const short* qbase = qn_ws + (size_t)((al + 24 * p) * SS) * HH + c * HH + g * 8;
#pragma unroll
        for (int ti = 0; ti < 6; ++ti) {
            f32x4 acc[6];
#pragma unroll
            for (int tj = 0; tj < 6; ++tj) acc[tj] = z4;
#pragma unroll
            for (int kk = 0; kk < 8; ++kk) {
                bf16x8 qf = *reinterpret_cast<const bf16x8*>(qbase + ti * 16 * HH + kk * 32);
#pragma unroll
                for (int tj = 0; tj < 6; ++tj) {
                    bf16x8 kf = *reinterpret_cast<const bf16x8*>(kbase + tj * 16 * HH + kk * 32);
                    acc[tj] = mfma16(kf, qf, acc[tj]);
                }
            }
#pragma unroll
            for (int tj = 0; tj < 6; ++tj) {
                float e0 = exp2f(acc[tj][0] * L2E10);
                float e1 = exp2f(acc[tj][1] * L2E10);
                float e2 = exp2f(acc[tj][2] * L2E10);
                float e3 = exp2f(acc[tj][3] * L2E10);
                Kp[p][ti][tj][0] = pk2bf(e0, e1);
                Kp[p][ti][tj][1] = pk2bf(e2, e3);
            }
        }
    }

    // ---- Sinkhorn scaling vectors, both pairs interleaved (ILP) ----
    f32x4 v[2][6];
#pragma unroll
    for (int p = 0; p < 2; ++p)
#pragma unroll
        for (int tj = 0; tj < 6; ++tj) v[p][tj] = (f32x4){1.f, 1.f, 1.f, 1.f};
    float u[2][6];

#pragma unroll 1
    for (int it = 0; it < 5; ++it) {
#pragma unroll
        for (int p = 0; p < 2; ++p)
#pragma unroll
            for (int ti = 0; ti < 6; ++ti) {
                float rs0 = 0.f, rs1 = 0.f;
#pragma unroll
                for (int tj = 0; tj < 6; ++tj) {
                    rs0 += ubflo(Kp[p][ti][tj][0]) * v[p][tj][0] +
                           ubflo(Kp[p][ti][tj][1]) * v[p][tj][2];
                    rs1 += ubfhi(Kp[p][ti][tj][0]) * v[p][tj][1] +
                           ubfhi(Kp[p][ti][tj][1]) * v[p][tj][3];
                }
                float rs = rs0 + rs1;
                rs += __shfl_xor(rs, 16);
                rs += __shfl_xor(rs, 32);
                u[p][ti] = 1.0f / rs;
            }
#pragma unroll
        for (int p = 0; p < 2; ++p)
#pragma unroll
            for (int tj = 0; tj < 6; ++tj) {
                f32x4 cs = z4;
#pragma unroll
                for (int ti = 0; ti < 6; ++ti) {
                    cs[0] += ubflo(Kp[p][ti][tj][0]) * u[p][ti];
                    cs[1] += ubfhi(Kp[p][ti][tj][0]) * u[p][ti];
                    cs[2] += ubflo(Kp[p][ti][tj][1]) * u[p][ti];
                    cs[3] += ubfhi(Kp[p][ti][tj][1]) * u[p][ti];
                }
#pragma unroll
                for (int m = 1; m < 16; m <<= 1)
#pragma unroll
                    for (int r = 0; r < 4; ++r) cs[r] += __shfl_xor(cs[r], m);
#pragma unroll
                for (int r = 0; r < 4; ++r) v[p][tj][r] = 1.0f / cs[r];
            }
    }

    // ---- final: W = K0*diag(v), row-L2 normalize, bf16 store, per pair ----
#pragma unroll
    for (int p = 0; p < 2; ++p) {
        short* tp = t_ws + (size_t)((al + 24 * p) * BB + b) * SS * SS;
#pragma unroll
        for (int ti = 0; ti < 6; ++ti) {
            float ss0 = 0.f, ss1 = 0.f;
#pragma unroll
            for (int tj = 0; tj < 6; ++tj) {
                float t0 = ubflo(Kp[p][ti][tj][0]) * v[p][tj][0];
                float t1 = ubfhi(Kp[p][ti][tj][0]) * v[p][tj][1];
                float t2 = ubflo(Kp[p][ti][tj][1]) * v[p][tj][2];
                float t3 = ubfhi(Kp[p][ti][tj][1]) * v[p][tj][3];
                ss0 += t0 * t0 + t2 * t2;
                ss1 += t1 * t1 + t3 * t3;
            }
            float ss = ss0 + ss1;
            ss += __shfl_xor(ss, 16);
            ss += __shfl_xor(ss, 32);
            float linv = 1.0f / fmaxf(sqrtf(ss), 1e-12f);
#pragma unroll
            for (int tj = 0; tj < 6; ++tj) {
                s16x4 pk;
                pk[0] = f2bf(ubflo(Kp[p][ti][tj][0]) * v[p][tj][0] * linv);
                pk[1] = f2bf(ubfhi(Kp[p][ti][tj][0]) * v[p][tj][1] * linv);
                pk[2] = f2bf(ubflo(Kp[p][ti][tj][1]) * v[p][tj][2] * linv);
                pk[3] = f2bf(ubfhi(Kp[p][ti][tj][1]) * v[p][tj][3] * linv);
                *reinterpret_cast<s16x4*>(tp + (16 * ti + c) * SS + 16 * tj + 4 * g) = pk;
            }
        }
    }
}

// ---------------------------------------------------------------------------
// Kernel 3a-fallback: sink_kernel — R10 exact (used only when ws forces
// chunking). One wave per pair, f32 K, (256,2).
// ---------------------------------------------------------------------------
__global__ __launch_bounds__(256, 2) void sink_kernel(
    const short* __restrict__ qn_ws, const short* __restrict__ kn_ws,
    short* __restrict__ t_ws, int a_off) {
    int wave = threadIdx.x >> 6, lane = threadIdx.x & 63;
    int c = lane & 15, g = lane >> 4;
    int b = blockIdx.x * 4 + wave;
    int al = blockIdx.y;
    int a = al + a_off;

    const short* qbase = qn_ws + (size_t)(a * SS) * HH + c * HH + g * 8;
    const short* kbase = kn_ws + (size_t)(b * SS) * HH + c * HH + g * 8;

    const f32x4 z4 = {0.f, 0.f, 0.f, 0.f};
    f32x4 K[6][6];
#pragma unroll
    for (int ti = 0; ti < 6; ++ti)
#pragma unroll
        for (int tj = 0; tj < 6; ++tj) K[ti][tj] = z4;

#pragma unroll
    for (int kk = 0; kk < 8; ++kk) {
        bf16x8 qf[6];
#pragma unroll
        for (int ti = 0; ti < 6; ++ti)
            qf[ti] = *reinterpret_cast<const bf16x8*>(qbase + ti * 16 * HH + kk * 32);
#pragma unroll
        for (int tj = 0; tj < 6; ++tj) {
            bf16x8 kf = *reinterpret_cast<const bf16x8*>(kbase + tj * 16 * HH + kk * 32);
#pragma unroll
            for (int ti = 0; ti < 6; ++ti)
                K[ti][tj] = mfma16(kf, qf[ti], K[ti][tj]);
        }
    }

#pragma unroll
    for (int ti = 0; ti < 6; ++ti)
#pragma unroll
        for (int tj = 0; tj < 6; ++tj)
#pragma unroll
            for (int r = 0; r < 4; ++r)
                K[ti][tj][r] = exp2f(K[ti][tj][r] * 14.4269504088896341f);

    f32x4 v[6];
#pragma unroll
    for (int tj = 0; tj < 6; ++tj) v[tj] = (f32x4){1.f, 1.f, 1.f, 1.f};
    float u[6];

#pragma unroll 1
    for (int it = 0; it < 5; ++it) {
#pragma unroll
        for (int ti = 0; ti < 6; ++ti) {
            f32x4 p0 = K[ti][0] * v[0] + K[ti][1] * v[1];
            f32x4 p1 = K[ti][2] * v[2] + K[ti][3] * v[3];
            f32x4 p2 = K[ti][4] * v[4] + K[ti][5] * v[5];
            f32x4 p = (p0 + p1) + p2;
            float rs = (p[0] + p[1]) + (p[2] + p[3]);
            rs += __shfl_xor(rs, 16);
            rs += __shfl_xor(rs, 32);
            u[ti] = 1.0f / rs;
        }
#pragma unroll
        for (int tj = 0; tj < 6; ++tj) {
            f32x4 c0 = K[0][tj] * u[0] + K[1][tj] * u[1];
            f32x4 c1 = K[2][tj] * u[2] + K[3][tj] * u[3];
            f32x4 c2 = K[4][tj] * u[4] + K[5][tj] * u[5];
            f32x4 cs = (c0 + c1) + c2;
#pragma unroll
            for (int m = 1; m < 16; m <<= 1)
#pragma unroll
                for (int r = 0; r < 4; ++r) cs[r] += __shfl_xor(cs[r], m);
#pragma unroll
            for (int r = 0; r < 4; ++r) v[tj][r] = 1.0f / cs[r];
        }
    }

    short* tp = t_ws + (size_t)(al * BB + b) * SS * SS;
#pragma unroll
    for (int ti = 0; ti < 6; ++ti) {
        f32x4 w[6];
#pragma unroll
        for (int tj = 0; tj < 6; ++tj) w[tj] = K[ti][tj] * v[tj];
        f32x4 q0 = w[0] * w[0] + w[1] * w[1];
        f32x4 q1 = w[2] * w[2] + w[3] * w[3];
        f32x4 q2 = w[4] * w[4] + w[5] * w[5];
        f32x4 qq = (q0 + q1) + q2;
        float ss = (qq[0] + qq[1]) + (qq[2] + qq[3]);
        ss += __shfl_xor(ss, 16);
        ss += __shfl_xor(ss, 32);
        float linv = 1.0f / fmaxf(sqrtf(ss), 1e-12f);
#pragma unroll
        for (int tj = 0; tj < 6; ++tj) {
            s16x4 pk;
#pragma unroll
            for (int r = 0; r < 4; ++r) pk[r] = f2bf(w[tj][r] * linv);
            *reinterpret_cast<s16x4*>(tp + (16 * ti + c) * SS + 16 * tj + 4 * g) = pk;
        }
    }
}

// ---------------------------------------------------------------------------
// Kernel 3b: pv_kernel — R13 exact (no swizzle: R16 -10us; no NT: R15 +40%
// write amp). mfma(A=vt,B=T): lane holds 4 contiguous d -> f32x4 stores.
// 512 thr = 8 waves, wave w owns d-slice [32w,32w+32) x all 96 i.
// ---------------------------------------------------------------------------
__global__ __launch_bounds__(512) void pv_kernel(
    const short* __restrict__ t_ws, const short* __restrict__ vt_ws,
    const float* __restrict__ q_ws,
    const float* __restrict__ ln_g, const float* __restrict__ ln_b,
    float* __restrict__ out, int a_off) {
    __shared__ float wstats[8][2][SS];     // 6144 B

    int b = blockIdx.x, al = blockIdx.y;
    int a = al + a_off;
    int tid = threadIdx.x;
    int w = tid >> 6, lane = tid & 63;
    int c = lane & 15, g = lane >> 4;
    int d0 = w * 32;

    const f32x4 z4 = {0.f, 0.f, 0.f, 0.f};
    f32x4 acc[2][6];
#pragma unroll
    for (int dt = 0; dt < 2; ++dt)
#pragma unroll
        for (int ti = 0; ti < 6; ++ti) acc[dt][ti] = z4;

    const short* vp = vt_ws + ((size_t)(b * HH) + d0 + c) * SS + g * 8;
    const short* tp = t_ws + ((size_t)(al * BB + b)) * SS * SS + c * SS + g * 8;
#pragma unroll
    for (int ks = 0; ks < 3; ++ks) {
        bf16x8 af0 = *reinterpret_cast<const bf16x8*>(vp + ks * 32);
        bf16x8 af1 = *reinterpret_cast<const bf16x8*>(vp + 16 * SS + ks * 32);
#pragma unroll
        for (int ti = 0; ti < 6; ++ti) {
            bf16x8 bf = *reinterpret_cast<const bf16x8*>(tp + ti * 16 * SS + ks * 32);
            acc[0][ti] = mfma16(af0, bf, acc[0][ti]);
            acc[1][ti] = mfma16(af1, bf, acc[1][ti]);
        }
    }

    const float* qa = q_ws + (size_t)a * SS * HH;
#pragma unroll
    for (int ti = 0; ti < 6; ++ti) {
        int i = 16 * ti + c;
        f32x4 q0 = *reinterpret_cast<const f32x4*>(qa + (size_t)i * HH + d0 + 4 * g);
        f32x4 q1 = *reinterpret_cast<const f32x4*>(qa + (size_t)i * HH + d0 + 16 + 4 * g);
        f32x4 x0 = acc[0][ti] + q0;
        f32x4 x1 = acc[1][ti] + q1;
        acc[0][ti] = x0;
        acc[1][ti] = x1;
        f32x4 sv = x0 + x1;
        f32x4 qv = x0 * x0 + x1 * x1;
        float l1 = (sv[0] + sv[1]) + (sv[2] + sv[3]);
        float l2 = (qv[0] + qv[1]) + (qv[2] + qv[3]);
        l1 += __shfl_xor(l1, 16);
        l1 += __shfl_xor(l1, 32);
        l2 += __shfl_xor(l2, 16);
        l2 += __shfl_xor(l2, 32);
        if (g == 0) {
            wstats[w][0][i] = l1;
            wstats[w][1][i] = l2;
        }
    }
    __syncthreads();

    f32x4 g4[2], b4[2];
#pragma unroll
    for (int dt = 0; dt < 2; ++dt) {
        g4[dt] = *reinterpret_cast<const f32x4*>(ln_g + d0 + dt * 16 + 4 * g);
        b4[dt] = *reinterpret_cast<const f32x4*>(ln_b + d0 + dt * 16 + 4 * g);
    }

    float* ob = out + ((size_t)(a * BB + b)) * SS * HH;
#pragma unroll
    for (int ti = 0; ti < 6; ++ti) {
        int i = 16 * ti + c;
        float t1 = ((wstats[0][0][i] + wstats[1][0][i]) + (wstats[2][0][i] + wstats[3][0][i])) +
                   ((wstats[4][0][i] + wstats[5][0][i]) + (wstats[6][0][i] + wstats[7][0][i]));
        float t2 = ((wstats[0][1][i] + wstats[1][1][i]) + (wstats[2][1][i] + wstats[3][1][i])) +
                   ((wstats[4][1][i] + wstats[5][1][i]) + (wstats[6][1][i] + wstats[7][1][i]));
        float mean = t1 * (1.0f / 256.0f);
        float var = t2 * (1.0f / 256.0f) - mean * mean;
        float inv = rsqrtf(var + 1e-5f);
#pragma unroll
        for (int dt = 0; dt < 2; ++dt) {
            f32x4 x = acc[dt][ti];
            f32x4 o;
#pragma unroll
            for (int r = 0; r < 4; ++r)
                o[r] = (x[r] - mean) * inv * g4[dt][r] + b4[dt][r];
            *reinterpret_cast<f32x4*>(ob + (size_t)i * HH + d0 + dt * 16 + 4 * g) = o;
        }
    }
}

// ---------------------------------------------------------------------------
extern "C" void kernel_launch(void* const* d_in, const int* in_sizes, int n_in,
                              void* d_out, int out_size, void* d_ws, size_t ws_size,
                              hipStream_t stream) {
    const float* Xa = (const float*)d_in[0];
    const float* Xb = (const float*)d_in[1];
    const float* Wq = (const float*)d_in[2];
    const float* bq = (const float*)d_in[3];
    const float* Wk = (const float*)d_in[4];
    const float* bk = (const float*)d_in[5];
    const float* Wv = (const float*)d_in[6];
    const float* bv = (const float*)d_in[7];
    const float* ln_g = (const float*)d_in[8];
    const float* ln_b = (const float*)d_in[9];
    float* out = (float*)d_out;

    char* ws = (char*)d_ws;
    short* wt    = (short*)(ws);               //  0         .. 1,179,648
    short* xa_bf = (short*)(ws + 1179648);     //  7,077,888 B
    short* xb_bf = (short*)(ws + 8257536);     //  7,077,888 B
    float* q_ws  = (float*)(ws + 15335424);    //  4,718,592 B
    float* k_ws  = (float*)(ws + 20054016);    //  4,718,592 B (dead after norm)
    short* qn_ws = (short*)(ws + 24772608);    //  2,359,296 B
    short* kn_ws = (short*)(ws + 27131904);    //  2,359,296 B
    short* vt_ws = (short*)(ws + 29491200);    //  2,359,296 B (end 31,850,496)

    // T buffer: 48x48x96x96 bf16 = 42,467,328 B; chunk if ws is small.
    const size_t t_full = (size_t)BA * BB * SS * SS * 2;
    size_t t_off = 31850496;
    size_t avail = (ws_size > t_off) ? ws_size - t_off : 0;
    int nch;
    if (avail >= t_full) nch = 1;
    else if (avail >= t_full / 2) nch = 2;
    else if (avail >= t_full / 4) nch = 4;
    else { nch = 4; t_off = 0; }  // overlay dead wt/xa/xb region (10.62 MB <= 15.3 MB)
    short* t_ws = (short*)(ws + t_off);
    int apc = BA / nch;

    prep_kernel<<<dim3(3600), dim3(256), 0, stream>>>(Xa, Xb, Wq, Wk, Wv,
                                                      xa_bf, xb_bf, wt);
    qkv_kernel<<<dim3(BA, 3, 8), dim3(384), 0, stream>>>(xa_bf, xb_bf, bq, bk, bv, wt,
                                                         q_ws, k_ws, vt_ws);
    norm_kernel<<<dim3(2304), dim3(256), 0, stream>>>(q_ws, k_ws, qn_ws, kn_ws);
    if (nch == 1) {
        sink2_kernel<<<dim3(12, 24), dim3(256), 0, stream>>>(qn_ws, kn_ws, t_ws);
        pv_kernel<<<dim3(BB, BA), dim3(512), 0, stream>>>(t_ws, vt_ws, q_ws,
                                                          ln_g, ln_b, out, 0);
    } else {
        for (int ch = 0; ch < nch; ++ch) {
            sink_kernel<<<dim3(12, apc), dim3(256), 0, stream>>>(qn_ws, kn_ws, t_ws, ch * apc);
            pv_kernel<<<dim3(BB, apc), dim3(512), 0, stream>>>(t_ws, vt_ws, q_ws,
                                                               ln_g, ln_b, out, ch * apc);
        }
    }
}

// Round 18
// 238.014 us; speedup vs baseline: 1.7936x; 1.7936x over previous
//
#include <hip/hip_runtime.h>
#include <hip/hip_bf16.h>

typedef __attribute__((ext_vector_type(4))) float f32x4;
typedef __attribute__((ext_vector_type(8))) short bf16x8;
typedef __attribute__((ext_vector_type(4))) short s16x4;

#define BA 48
#define BB 48
#define SS 96
#define DIN 768
#define HH 256

static __device__ __forceinline__ short f2bf(float f) {
    __hip_bfloat16 h = __float2bfloat16(f);
    return *reinterpret_cast<short*>(&h);
}

static __device__ __forceinline__ f32x4 mfma16(bf16x8 a, bf16x8 b, f32x4 c) {
    return __builtin_amdgcn_mfma_f32_16x16x32_bf16(a, b, c, 0, 0, 0);
}

// ---------------------------------------------------------------------------
// Kernel 0: prep — fused {xbf: X f32->bf16, blocks 0..3455} and
// {wt: W transpose+convert, blocks 3456..3599}. Single launch, components
// byte-identical to R13's wt_kernel/xbf_kernel bodies.
// ---------------------------------------------------------------------------
__global__ __launch_bounds__(256) void prep_kernel(
    const float* __restrict__ Xa, const float* __restrict__ Xb,
    const float* __restrict__ Wq, const float* __restrict__ Wk,
    const float* __restrict__ Wv,
    short* __restrict__ xa, short* __restrict__ xb, short* __restrict__ wt) {
    __shared__ float tile[64][65];
    int bx = blockIdx.x;
    if (bx < 3456) {
        size_t i = (size_t)bx * 256 + threadIdx.x;
        const float* src;
        short* dst;
        size_t off;
        if (i < 442368) { src = Xa; dst = xa; off = i * 8; }
        else            { src = Xb; dst = xb; off = (i - 442368) * 8; }
        f32x4 a = *reinterpret_cast<const f32x4*>(src + off);
        f32x4 b = *reinterpret_cast<const f32x4*>(src + off + 4);
        bf16x8 o;
        o[0] = f2bf(a[0]); o[1] = f2bf(a[1]); o[2] = f2bf(a[2]); o[3] = f2bf(a[3]);
        o[4] = f2bf(b[0]); o[5] = f2bf(b[1]); o[6] = f2bf(b[2]); o[7] = f2bf(b[3]);
        *reinterpret_cast<bf16x8*>(dst + off) = o;
    } else {
        int tt = bx - 3456;                 // 0..143
        int k0 = (tt % 12) * 64;
        int n0 = ((tt / 12) % 4) * 64;
        int mat = tt / 48;
        const float* W = (mat == 0) ? Wq : (mat == 1) ? Wk : Wv;
        int t = threadIdx.x;
#pragma unroll
        for (int j = 0; j < 16; ++j) {
            int kk = j * 4 + (t >> 6);
            int nn = t & 63;
            tile[kk][nn] = W[(size_t)(k0 + kk) * HH + n0 + nn];
        }
        __syncthreads();
#pragma unroll
        for (int j = 0; j < 4; ++j) {
            int nn = j * 16 + (t >> 4);
            int kk = (t & 15) * 4;
            s16x4 pk;
#pragma unroll
            for (int i = 0; i < 4; ++i) pk[i] = f2bf(tile[kk + i][nn]);
            *reinterpret_cast<s16x4*>(&wt[(size_t)(mat * HH + n0 + nn) * DIN + k0 + kk]) = pk;
        }
    }
}

// ---------------------------------------------------------------------------
// Kernel 1: QKV projection from bf16 X. grid (48, 3, 8): 32-col tiles.
// ---------------------------------------------------------------------------
__global__ __launch_bounds__(384) void qkv_kernel(
    const short* __restrict__ xa, const short* __restrict__ xb,
    const float* __restrict__ bq, const float* __restrict__ bk, const float* __restrict__ bv,
    const short* __restrict__ wt,
    float* __restrict__ q_ws, float* __restrict__ k_ws, short* __restrict__ vt_ws) {
    __shared__ short vtile[32][104];

    int bb = blockIdx.x;
    int mat = blockIdx.y;
    int c0 = blockIdx.z * 32;
    int tid = threadIdx.x;
    int wave = tid >> 6, lane = tid & 63;
    int c = lane & 15, g = lane >> 4;

    const short* X = ((mat == 0) ? xa : xb) + (size_t)bb * SS * DIN;
    const short* Wt = wt + (size_t)mat * HH * DIN;
    const float* bias = (mat == 0) ? bq : (mat == 1) ? bk : bv;

    const f32x4 z4 = {0.f, 0.f, 0.f, 0.f};
    f32x4 acc[2];
    acc[0] = z4; acc[1] = z4;

    const short* ap = X + (16 * wave + c) * DIN + g * 8;
    const short* bp = Wt + (c0 + c) * DIN + g * 8;
    for (int kk = 0; kk < DIN; kk += 32) {
        bf16x8 af = *reinterpret_cast<const bf16x8*>(ap + kk);
#pragma unroll
        for (int n = 0; n < 2; ++n) {
            bf16x8 bf = *reinterpret_cast<const bf16x8*>(bp + n * 16 * DIN + kk);
            acc[n] = mfma16(af, bf, acc[n]);
        }
    }
#pragma unroll
    for (int n = 0; n < 2; ++n) {
        float bv_ = bias[c0 + n * 16 + c];
#pragma unroll
        for (int r = 0; r < 4; ++r) acc[n][r] += bv_;
    }

    if (mat < 2) {
        float* dst = (mat == 0) ? q_ws : k_ws;
#pragma unroll
        for (int n = 0; n < 2; ++n)
#pragma unroll
            for (int r = 0; r < 4; ++r)
                dst[(bb * SS + 16 * wave + 4 * g + r) * HH + c0 + n * 16 + c] = acc[n][r];
    } else {
#pragma unroll
        for (int n = 0; n < 2; ++n)
#pragma unroll
            for (int r = 0; r < 4; ++r)
                vtile[n * 16 + c][16 * wave + 4 * g + r] = f2bf(acc[n][r]);
        __syncthreads();
        {
            int t = tid;                 // 384 = 32 d x 12 ch exactly
            int d = t / 12, ch = t % 12;
            bf16x8 pk = *reinterpret_cast<const bf16x8*>(&vtile[d][ch * 8]);
            *reinterpret_cast<bf16x8*>(vt_ws + ((size_t)(bb * HH) + c0 + d) * SS + ch * 8) = pk;
        }
    }
}

// ---------------------------------------------------------------------------
// Kernel 2: row L2 norms for q,k -> qn,kn bf16. One wave per row.
// ---------------------------------------------------------------------------
__global__ __launch_bounds__(256) void norm_kernel(
    const float* __restrict__ q_ws, const float* __restrict__ k_ws,
    short* __restrict__ qn_ws, short* __restrict__ kn_ws) {
    int row = blockIdx.x * 4 + (threadIdx.x >> 6);
    int lane = threadIdx.x & 63;
    int isq = (row < 4608);
    const float* src = isq ? q_ws : k_ws;
    short* dst = isq ? qn_ws : kn_ws;
    int r = isq ? row : row - 4608;

    f32x4 v = *reinterpret_cast<const f32x4*>(src + (size_t)r * HH + lane * 4);
    float s = v[0] * v[0] + v[1] * v[1] + v[2] * v[2] + v[3] * v[3];
#pragma unroll
    for (int m = 1; m < 64; m <<= 1) s += __shfl_xor(s, m);
    float inv = 1.0f / fmaxf(sqrtf(s), 1e-8f);
    s16x4 o;
#pragma unroll
    for (int j = 0; j < 4; ++j) o[j] = f2bf(v[j] * inv);
    *reinterpret_cast<s16x4*>(dst + (size_t)r * HH + lane * 4) = o;
}

// ---------------------------------------------------------------------------
// Kernel 3a: sink_kernel — R10 exact, the ONLY stable register shape: one
// wave per (a,b) pair, K0 f32 144 regs (MFMA-native accumulators), scaling-
// vector Sinkhorn, zero barriers/LDS, (256,2). CLOSED experiments: forced
// caps (256,3)/(64,4)/(256,2)-packed all spill (R8/R12/R17); 2-wave split
// slower (R11); pv-fusion slower (R14); NT harmful (R15); swizzle -10us (R16).
// ---------------------------------------------------------------------------
__global__ __launch_bounds__(256, 2) void sink_kernel(
    const short* __restrict__ qn_ws, const short* __restrict__ kn_ws,
    short* __restrict__ t_ws, int a_off) {
    int wave = threadIdx.x >> 6, lane = threadIdx.x & 63;
    int c = lane & 15, g = lane >> 4;
    int b = blockIdx.x * 4 + wave;
    int al = blockIdx.y;
    int a = al + a_off;

    const short* qbase = qn_ws + (size_t)(a * SS) * HH + c * HH + g * 8;
    const short* kbase = kn_ws + (size_t)(b * SS) * HH + c * HH + g * 8;

    const f32x4 z4 = {0.f, 0.f, 0.f, 0.f};
    f32x4 K[6][6];
#pragma unroll
    for (int ti = 0; ti < 6; ++ti)
#pragma unroll
        for (int tj = 0; tj < 6; ++tj) K[ti][tj] = z4;

#pragma unroll
    for (int kk = 0; kk < 8; ++kk) {
        bf16x8 qf[6];
#pragma unroll
        for (int ti = 0; ti < 6; ++ti)
            qf[ti] = *reinterpret_cast<const bf16x8*>(qbase + ti * 16 * HH + kk * 32);
#pragma unroll
        for (int tj = 0; tj < 6; ++tj) {
            bf16x8 kf = *reinterpret_cast<const bf16x8*>(kbase + tj * 16 * HH + kk * 32);
#pragma unroll
            for (int ti = 0; ti < 6; ++ti)
                K[ti][tj] = mfma16(kf, qf[ti], K[ti][tj]);
        }
    }

#pragma unroll
    for (int ti = 0; ti < 6; ++ti)
#pragma unroll
        for (int tj = 0; tj < 6; ++tj)
#pragma unroll
            for (int r = 0; r < 4; ++r)
                K[ti][tj][r] = exp2f(K[ti][tj][r] * 14.4269504088896341f);

    f32x4 v[6];
#pragma unroll
    for (int tj = 0; tj < 6; ++tj) v[tj] = (f32x4){1.f, 1.f, 1.f, 1.f};
    float u[6];

#pragma unroll 1
    for (int it = 0; it < 5; ++it) {
#pragma unroll
        for (int ti = 0; ti < 6; ++ti) {
            f32x4 p0 = K[ti][0] * v[0] + K[ti][1] * v[1];
            f32x4 p1 = K[ti][2] * v[2] + K[ti][3] * v[3];
            f32x4 p2 = K[ti][4] * v[4] + K[ti][5] * v[5];
            f32x4 p = (p0 + p1) + p2;
            float rs = (p[0] + p[1]) + (p[2] + p[3]);
            rs += __shfl_xor(rs, 16);
            rs += __shfl_xor(rs, 32);
            u[ti] = 1.0f / rs;
        }
#pragma unroll
        for (int tj = 0; tj < 6; ++tj) {
            f32x4 c0 = K[0][tj] * u[0] + K[1][tj] * u[1];
            f32x4 c1 = K[2][tj] * u[2] + K[3][tj] * u[3];
            f32x4 c2 = K[4][tj] * u[4] + K[5][tj] * u[5];
            f32x4 cs = (c0 + c1) + c2;
#pragma unroll
            for (int m = 1; m < 16; m <<= 1)
#pragma unroll
                for (int r = 0; r < 4; ++r) cs[r] += __shfl_xor(cs[r], m);
#pragma unroll
            for (int r = 0; r < 4; ++r) v[tj][r] = 1.0f / cs[r];
        }
    }

    short* tp = t_ws + (size_t)(al * BB + b) * SS * SS;
#pragma unroll
    for (int ti = 0; ti < 6; ++ti) {
        f32x4 w[6];
#pragma unroll
        for (int tj = 0; tj < 6; ++tj) w[tj] = K[ti][tj] * v[tj];
        f32x4 q0 = w[0] * w[0] + w[1] * w[1];
        f32x4 q1 = w[2] * w[2] + w[3] * w[3];
        f32x4 q2 = w[4] * w[4] + w[5] * w[5];
        f32x4 qq = (q0 + q1) + q2;
        float ss = (qq[0] + qq[1]) + (qq[2] + qq[3]);
        ss += __shfl_xor(ss, 16);
        ss += __shfl_xor(ss, 32);
        float linv = 1.0f / fmaxf(sqrtf(ss), 1e-12f);
#pragma unroll
        for (int tj = 0; tj < 6; ++tj) {
            s16x4 pk;
#pragma unroll
            for (int r = 0; r < 4; ++r) pk[r] = f2bf(w[tj][r] * linv);
            *reinterpret_cast<s16x4*>(tp + (16 * ti + c) * SS + 16 * tj + 4 * g) = pk;
        }
    }
}

// ---------------------------------------------------------------------------
// Kernel 3b: pv_kernel — R13 exact (no swizzle: R16 -10us; no NT: R15 +40%
// write amp). mfma(A=vt,B=T): lane holds 4 contiguous d -> f32x4 stores.
// 512 thr = 8 waves, wave w owns d-slice [32w,32w+32) x all 96 i.
// ---------------------------------------------------------------------------
__global__ __launch_bounds__(512) void pv_kernel(
    const short* __restrict__ t_ws, const short* __restrict__ vt_ws,
    const float* __restrict__ q_ws,
    const float* __restrict__ ln_g, const float* __restrict__ ln_b,
    float* __restrict__ out, int a_off) {
    __shared__ float wstats[8][2][SS];     // 6144 B

    int b = blockIdx.x, al = blockIdx.y;
    int a = al + a_off;
    int tid = threadIdx.x;
    int w = tid >> 6, lane = tid & 63;
    int c = lane & 15, g = lane >> 4;
    int d0 = w * 32;

    const f32x4 z4 = {0.f, 0.f, 0.f, 0.f};
    f32x4 acc[2][6];
#pragma unroll
    for (int dt = 0; dt < 2; ++dt)
#pragma unroll
        for (int ti = 0; ti < 6; ++ti) acc[dt][ti] = z4;

    const short* vp = vt_ws + ((size_t)(b * HH) + d0 + c) * SS + g * 8;
    const short* tp = t_ws + ((size_t)(al * BB + b)) * SS * SS + c * SS + g * 8;
#pragma unroll
    for (int ks = 0; ks < 3; ++ks) {
        bf16x8 af0 = *reinterpret_cast<const bf16x8*>(vp + ks * 32);
        bf16x8 af1 = *reinterpret_cast<const bf16x8*>(vp + 16 * SS + ks * 32);
#pragma unroll
        for (int ti = 0; ti < 6; ++ti) {
            bf16x8 bf = *reinterpret_cast<const bf16x8*>(tp + ti * 16 * SS + ks * 32);
            acc[0][ti] = mfma16(af0, bf, acc[0][ti]);
            acc[1][ti] = mfma16(af1, bf, acc[1][ti]);
        }
    }

    const float* qa = q_ws + (size_t)a * SS * HH;
#pragma unroll
    for (int ti = 0; ti < 6; ++ti) {
        int i = 16 * ti + c;
        f32x4 q0 = *reinterpret_cast<const f32x4*>(qa + (size_t)i * HH + d0 + 4 * g);
        f32x4 q1 = *reinterpret_cast<const f32x4*>(qa + (size_t)i * HH + d0 + 16 + 4 * g);
        f32x4 x0 = acc[0][ti] + q0;
        f32x4 x1 = acc[1][ti] + q1;
        acc[0][ti] = x0;
        acc[1][ti] = x1;
        f32x4 sv = x0 + x1;
        f32x4 qv = x0 * x0 + x1 * x1;
        float l1 = (sv[0] + sv[1]) + (sv[2] + sv[3]);
        float l2 = (qv[0] + qv[1]) + (qv[2] + qv[3]);
        l1 += __shfl_xor(l1, 16);
        l1 += __shfl_xor(l1, 32);
        l2 += __shfl_xor(l2, 16);
        l2 += __shfl_xor(l2, 32);
        if (g == 0) {
            wstats[w][0][i] = l1;
            wstats[w][1][i] = l2;
        }
    }
    __syncthreads();

    f32x4 g4[2], b4[2];
#pragma unroll
    for (int dt = 0; dt < 2; ++dt) {
        g4[dt] = *reinterpret_cast<const f32x4*>(ln_g + d0 + dt * 16 + 4 * g);
        b4[dt] = *reinterpret_cast<const f32x4*>(ln_b + d0 + dt * 16 + 4 * g);
    }

    float* ob = out + ((size_t)(a * BB + b)) * SS * HH;
#pragma unroll
    for (int ti = 0; ti < 6; ++ti) {
        int i = 16 * ti + c;
        float t1 = ((wstats[0][0][i] + wstats[1][0][i]) + (wstats[2][0][i] + wstats[3][0][i])) +
                   ((wstats[4][0][i] + wstats[5][0][i]) + (wstats[6][0][i] + wstats[7][0][i]));
        float t2 = ((wstats[0][1][i] + wstats[1][1][i]) + (wstats[2][1][i] + wstats[3][1][i])) +
                   ((wstats[4][1][i] + wstats[5][1][i]) + (wstats[6][1][i] + wstats[7][1][i]));
        float mean = t1 * (1.0f / 256.0f);
        float var = t2 * (1.0f / 256.0f) - mean * mean;
        float inv = rsqrtf(var + 1e-5f);
#pragma unroll
        for (int dt = 0; dt < 2; ++dt) {
            f32x4 x = acc[dt][ti];
            f32x4 o;
#pragma unroll
            for (int r = 0; r < 4; ++r)
                o[r] = (x[r] - mean) * inv * g4[dt][r] + b4[dt][r];
            *reinterpret_cast<f32x4*>(ob + (size_t)i * HH + d0 + dt * 16 + 4 * g) = o;
        }
    }
}

// ---------------------------------------------------------------------------
extern "C" void kernel_launch(void* const* d_in, const int* in_sizes, int n_in,
                              void* d_out, int out_size, void* d_ws, size_t ws_size,
                              hipStream_t stream) {
    const float* Xa = (const float*)d_in[0];
    const float* Xb = (const float*)d_in[1];
    const float* Wq = (const float*)d_in[2];
    const float* bq = (const float*)d_in[3];
    const float* Wk = (const float*)d_in[4];
    const float* bk = (const float*)d_in[5];
    const float* Wv = (const float*)d_in[6];
    const float* bv = (const float*)d_in[7];
    const float* ln_g = (const float*)d_in[8];
    const float* ln_b = (const float*)d_in[9];
    float* out = (float*)d_out;

    char* ws = (char*)d_ws;
    short* wt    = (short*)(ws);               //  0         .. 1,179,648
    short* xa_bf = (short*)(ws + 1179648);     //  7,077,888 B
    short* xb_bf = (short*)(ws + 8257536);     //  7,077,888 B
    float* q_ws  = (float*)(ws + 15335424);    //  4,718,592 B
    float* k_ws  = (float*)(ws + 20054016);    //  4,718,592 B (dead after norm)
    short* qn_ws = (short*)(ws + 24772608);    //  2,359,296 B
    short* kn_ws = (short*)(ws + 27131904);    //  2,359,296 B
    short* vt_ws = (short*)(ws + 29491200);    //  2,359,296 B (end 31,850,496)

    // T buffer: 48x48x96x96 bf16 = 42,467,328 B; chunk if ws is small.
    const size_t t_full = (size_t)BA * BB * SS * SS * 2;
    size_t t_off = 31850496;
    size_t avail = (ws_size > t_off) ? ws_size - t_off : 0;
    int nch;
    if (avail >= t_full) nch = 1;
    else if (avail >= t_full / 2) nch = 2;
    else if (avail >= t_full / 4) nch = 4;
    else { nch = 4; t_off = 0; }  // overlay dead wt/xa/xb region (10.62 MB <= 15.3 MB)
    short* t_ws = (short*)(ws + t_off);
    int apc = BA / nch;

    prep_kernel<<<dim3(3600), dim3(256), 0, stream>>>(Xa, Xb, Wq, Wk, Wv,
                                                      xa_bf, xb_bf, wt);
    qkv_kernel<<<dim3(BA, 3, 8), dim3(384), 0, stream>>>(xa_bf, xb_bf, bq, bk, bv, wt,
                                                         q_ws, k_ws, vt_ws);
    norm_kernel<<<dim3(2304), dim3(256), 0, stream>>>(q_ws, k_ws, qn_ws, kn_ws);
    for (int ch = 0; ch < nch; ++ch) {
        sink_kernel<<<dim3(12, apc), dim3(256), 0, stream>>>(qn_ws, kn_ws, t_ws, ch * apc);
        pv_kernel<<<dim3(BB, apc), dim3(512), 0, stream>>>(t_ws, vt_ws, q_ws,
                                                           ln_g, ln_b, out, ch * apc);
    }
}